// Round 6
// baseline (604.519 us; speedup 1.0000x reference)
//
#include <hip/hip_runtime.h>
#include <hip/hip_bf16.h>
#include <math.h>

// Problem constants (TransformerBlock: B=4,S=2048,D=1024,H=16,DFF=4096)
#define B_   4
#define S_   2048
#define D_   1024
#define H_   16
#define DK_  64
#define DFF_ 4096
#define M_   (B_*S_)   // 8192 rows

typedef __bf16 bf16;
typedef bf16 bf16x8 __attribute__((ext_vector_type(8)));
typedef bf16 bf16x4 __attribute__((ext_vector_type(4)));
typedef float f32x4 __attribute__((ext_vector_type(4)));

// ---- async global->LDS, 16B per lane, wave-uniform LDS base + lane*16 ----
__device__ __forceinline__ void g2lds16(const void* g, void* l) {
  __builtin_amdgcn_global_load_lds(
      (__attribute__((address_space(1))) void*)(void*)g,
      (__attribute__((address_space(3))) void*)l, 16, 0, 0);
}

// XOR swizzle for LDS tiles with 128-byte rows (T2 / Guideline-4 fix)
__device__ __forceinline__ void* swzp(char* base, int row, int byteofs) {
  return base + row * 128 + (byteofs ^ ((row & 7) << 4));
}

// sync/wait primitives for the 8-phase schedule
#define FENCE_ asm volatile("" ::: "memory")
#define BARR_  do { FENCE_; __builtin_amdgcn_s_barrier(); FENCE_; } while (0)
#define VMW4_  asm volatile("s_waitcnt vmcnt(4)" ::: "memory")
#define VMW0_  asm volatile("s_waitcnt vmcnt(0)" ::: "memory")
#define LGW_   do { asm volatile("s_waitcnt lgkmcnt(0)" ::: "memory"); \
                    __builtin_amdgcn_sched_barrier(0); } while (0)

// =====================================================================
// All weight casts+transposes in ONE kernel (W[K][N] f32 -> Wt[N][K] bf16)
// =====================================================================
__global__ void tcast_all(const float* __restrict__ Wq, const float* __restrict__ Wk,
                          const float* __restrict__ Wo, const float* __restrict__ W1,
                          const float* __restrict__ W2,
                          bf16* __restrict__ WqkT, bf16* __restrict__ WoT,
                          bf16* __restrict__ W1T, bf16* __restrict__ W2T) {
  __shared__ float t[32][33];
  int bid = blockIdx.x;
  const float* src; bf16* dst; int K, N, bx, by;
  if (bid < 1024)      { src = Wq; dst = WqkT;            K = 1024; N = 1024; bx = bid & 31;  by = bid >> 5; }
  else if (bid < 2048) { bid -= 1024; src = Wk; dst = WqkT + 1024 * 1024; K = 1024; N = 1024; bx = bid & 31;  by = bid >> 5; }
  else if (bid < 3072) { bid -= 2048; src = Wo; dst = WoT; K = 1024; N = 1024; bx = bid & 31;  by = bid >> 5; }
  else if (bid < 7168) { bid -= 3072; src = W1; dst = W1T; K = 1024; N = 4096; bx = bid & 127; by = bid >> 7; }
  else                 { bid -= 7168; src = W2; dst = W2T; K = 4096; N = 1024; bx = bid & 31;  by = bid >> 5; }
  int n0 = bx * 32, k0 = by * 32;
  int tx = threadIdx.x, ty = threadIdx.y;
#pragma unroll
  for (int i = 0; i < 4; ++i)
    t[ty + i*8][tx] = src[(size_t)(k0 + ty + i*8) * N + n0 + tx];
  __syncthreads();
#pragma unroll
  for (int i = 0; i < 4; ++i)
    dst[(size_t)(n0 + ty + i*8) * K + k0 + tx] = (bf16)t[tx][ty + i*8];
}

// =====================================================================
// K transpose (per head): Kt[B,H,S,64] bf16 -> KT[B,H,64,S] bf16
// =====================================================================
__global__ __launch_bounds__(256)
void ktrans(const bf16* __restrict__ Kt, bf16* __restrict__ KT) {
  __shared__ bf16 t[64][72];
  const int bh = blockIdx.y, s0 = blockIdx.x * 64, tid = threadIdx.x;
  const bf16* src = Kt + (size_t)bh * S_ * DK_;
  bf16* dst = KT + (size_t)bh * DK_ * S_;
#pragma unroll
  for (int i = 0; i < 2; ++i) {
    int c = tid * 2 + i;
    int r = c >> 3, col = (c & 7) * 8;
    *(bf16x8*)&t[r][col] = *(const bf16x8*)&src[(size_t)(s0 + r) * 64 + col];
  }
  __syncthreads();
  const int d = tid >> 2, sc = (tid & 3) * 16;
  bf16x8 v0, v1;
#pragma unroll
  for (int j = 0; j < 8; ++j) { v0[j] = t[sc + j][d]; v1[j] = t[sc + 8 + j][d]; }
  *(bf16x8*)&dst[(size_t)d * S_ + s0 + sc] = v0;
  *(bf16x8*)&dst[(size_t)d * S_ + s0 + sc + 8] = v1;
}

// =====================================================================
// LayerNorm over D=1024, one block (256 thr) per row, bf16 output
// =====================================================================
__global__ __launch_bounds__(256)
void ln_fwd(const float* __restrict__ x, const float* __restrict__ g,
            const float* __restrict__ be, bf16* __restrict__ out) {
  int row = blockIdx.x, tid = threadIdx.x;
  const float4 v = *(const float4*)&x[(size_t)row * D_ + tid * 4];
  float s = v.x + v.y + v.z + v.w;
  float q = v.x*v.x + v.y*v.y + v.z*v.z + v.w*v.w;
#pragma unroll
  for (int d = 32; d; d >>= 1) { s += __shfl_down(s, d); q += __shfl_down(q, d); }
  __shared__ float red[8];
  int wave = tid >> 6, lane = tid & 63;
  if (lane == 0) { red[wave*2] = s; red[wave*2+1] = q; }
  __syncthreads();
  float ts = red[0] + red[2] + red[4] + red[6];
  float tq = red[1] + red[3] + red[5] + red[7];
  float mean = ts * (1.0f / D_);
  float var  = tq * (1.0f / D_) - mean * mean;
  float rstd = rsqrtf(var + 1e-5f);
  const float4 gg = *(const float4*)&g[tid * 4];
  const float4 bb = *(const float4*)&be[tid * 4];
  bf16x4 ov;
  ov[0] = (bf16)((v.x - mean) * rstd * gg.x + bb.x);
  ov[1] = (bf16)((v.y - mean) * rstd * gg.y + bb.y);
  ov[2] = (bf16)((v.z - mean) * rstd * gg.z + bb.z);
  ov[3] = (bf16)((v.w - mean) * rstd * gg.w + bb.w);
  *(bf16x4*)&out[(size_t)row * D_ + tid * 4] = ov;
}

// =====================================================================
// 256x256x(BK=64) 8-phase GEMM (doc §5 template, T1+T2+T3+T4+T5).
// C[M,N] = A[M,KK] @ Bt[N,KK]^T, bf16 in, f32 acc. 512 thr = 8 waves
// (2M x 4N), per-wave 128x64 out = acc[8][4]. LDS 128 KiB (2 dbuf).
// Staging: half-tile = 128 rows x 64 cols = 2 global_load_lds per wave,
// XOR-pre-swizzled global source + linear LDS dest; reads XOR-swizzled.
// Counted vmcnt(4) at phases 0/4 only — never drained in main loop.
// Schedule (iter computes tiles t=2i [buf0] and t+1 [buf1]):
//   ph0: rd A(mi0-3)+B(ni0-1) buf0 | stg Ah0(t+1)->buf1 | MFMA q(0,0)
//   ph1: rd B(ni2-3)          buf0 | stg Ah1(t+1)->buf1 | MFMA q(0,1)
//   ph2: rd A(mi4-7)          buf0 | stg Bh0(t+2)->buf0 | MFMA q(1,0)
//   ph3:                           | stg Bh1(t+2)->buf0 | MFMA q(1,1)
//   ph4-7: same on buf1 / stg Ah(t+2)->buf0, Bh(t+3)->buf1
// Invariants (re-audited r5): a slot is overwritten only after the
// phase-END barrier following the last ds_read of it (reads retired via
// lgkmcnt(0) before MFMA before barrier); vmcnt(4)+barrier at ph0/ph4
// collectively guarantees the next tile's 8 loads landed in ALL waves;
// tail stages are k-clamped (written, never read), drained by VMW0.
// =====================================================================
template <int EPI, int KK>
__global__ __launch_bounds__(512, 2)
void gemm8p(const bf16* __restrict__ A, const bf16* __restrict__ Bt, int N,
            const float* __restrict__ bias, const float* __restrict__ bias2,
            const float* __restrict__ resid, float scale,
            float* __restrict__ outf, bf16* __restrict__ outb,
            bf16* __restrict__ outb2) {
  constexpr int NT = KK / 64;          // K-tiles (16 or 64, even)
  __shared__ __align__(16) bf16 Ab[2][256 * 64];
  __shared__ __align__(16) bf16 Bb[2][256 * 64];
  const int tid = threadIdx.x, wave = tid >> 6, lane = tid & 63;
  const int wr = wave >> 2, wc = wave & 3;
  const int l15 = lane & 15, q4 = lane >> 4;

  const int gx = gridDim.x, nwg = gx * gridDim.y;
  int wg = blockIdx.y * gx + blockIdx.x;
  wg = (wg & 7) * (nwg >> 3) + (wg >> 3);      // XCD chunking (bijective)
  const long arow = (long)(wg / gx) * 256;
  const long bcol = (long)(wg % gx) * 256;

  // staging lane geometry: chunk = 8 rows x 128B; src slot pre-swizzled
  const int srow  = lane >> 3;
  const int sslot = (lane & 7) ^ srow;
  const bf16* gA = A  + (size_t)(arow + wave * 16 + srow) * KK + sslot * 8;
  const bf16* gB = Bt + (size_t)(bcol + wave * 16 + srow) * KK + sslot * 8;

  // frag-read bases (byte offsets into 256x128B tiles, XOR-swizzled)
  char* const ab0 = (char*)&Ab[0][0];
  char* const ab1 = (char*)&Ab[1][0];
  char* const bb0 = (char*)&Bb[0][0];
  char* const bb1 = (char*)&Bb[1][0];
  const int aoff0 = (wr * 128 + l15) * 128;
  const int boff0 = (wc * 64 + l15) * 128;
  const int sw    = (l15 & 7) << 4;
  const int kq0   = (q4 * 16) ^ sw;
  const int kq1   = (64 + q4 * 16) ^ sw;

  f32x4 acc[8][4] = {};
  bf16x8 af[4][2], bq[4][2];

// stage one half-tile (2 g2lds per wave): dst = Ab[b]/Bb[b], gsrc = gA/gB
#define STG(dst, gsrc, half, kt) do {                                        \
    long kc_ = (long)(((kt) < NT) ? (kt) : (NT - 1)) * 64;                   \
    g2lds16((gsrc) + (long)((half) * 128) * KK + kc_,                        \
            &(dst)[((half) * 128 + wave * 16) * 64]);                        \
    g2lds16((gsrc) + (long)((half) * 128 + 8) * KK + kc_,                    \
            &(dst)[((half) * 128 + wave * 16 + 8) * 64]);                    \
  } while (0)

#define RDA(base, half) do {                                                 \
    _Pragma("unroll")                                                        \
    for (int m_ = 0; m_ < 4; ++m_) {                                         \
      af[m_][0] = *(const bf16x8*)((base) + aoff0 + ((half)*4+m_)*2048 + kq0);\
      af[m_][1] = *(const bf16x8*)((base) + aoff0 + ((half)*4+m_)*2048 + kq1);\
    } } while (0)

#define RDB(base, nh) do {                                                   \
    _Pragma("unroll")                                                        \
    for (int n_ = 0; n_ < 2; ++n_) {                                         \
      bq[(nh)*2+n_][0] = *(const bf16x8*)((base) + boff0 + ((nh)*2+n_)*2048 + kq0);\
      bq[(nh)*2+n_][1] = *(const bf16x8*)((base) + boff0 + ((nh)*2+n_)*2048 + kq1);\
    } } while (0)

#define QUAD(mh, nh) do {                                                    \
    __builtin_amdgcn_s_setprio(1);                                          \
    _Pragma("unroll")                                                        \
    for (int ks_ = 0; ks_ < 2; ++ks_)                                        \
      _Pragma("unroll")                                                      \
      for (int m_ = 0; m_ < 4; ++m_)                                         \
        _Pragma("unroll")                                                    \
        for (int n_ = 0; n_ < 2; ++n_)                                       \
          acc[(mh)*4+m_][(nh)*2+n_] = __builtin_amdgcn_mfma_f32_16x16x32_bf16(\
              af[m_][ks_], bq[(nh)*2+n_][ks_], acc[(mh)*4+m_][(nh)*2+n_],    \
              0, 0, 0);                                                      \
    __builtin_amdgcn_s_setprio(0);                                          \
  } while (0)

  // prologue: Bh(0)x2, Ah(0)x2, Bh(1)x2  (12 instr/wave in flight)
  STG(Bb[0], gB, 0, 0); STG(Bb[0], gB, 1, 0);
  STG(Ab[0], gA, 0, 0); STG(Ab[0], gA, 1, 0);
  STG(Bb[1], gB, 0, 1); STG(Bb[1], gB, 1, 1);

  for (int it = 0; it < NT / 2; ++it) {
    const int t = it * 2;
    // ---- ph0 (tile t, buf0, quad mi0-3 x ni0-1)
    VMW4_; BARR_;                      // oldest 8 = tile t fully landed
    RDA(ab0, 0); RDB(bb0, 0);
    STG(Ab[1], gA, 0, t + 1);
    LGW_; QUAD(0, 0); BARR_;
    // ---- ph1 (quad mi0-3 x ni2-3)
    RDB(bb0, 1);
    STG(Ab[1], gA, 1, t + 1);
    LGW_; QUAD(0, 1); BARR_;
    // ---- ph2 (quad mi4-7 x ni0-1)
    RDA(ab0, 1);
    STG(Bb[0], gB, 0, t + 2);
    LGW_; QUAD(1, 0); BARR_;
    // ---- ph3 (quad mi4-7 x ni2-3)
    STG(Bb[0], gB, 1, t + 2);
    QUAD(1, 1); BARR_;
    // ---- ph4 (tile t+1, buf1)
    VMW4_; BARR_;                      // oldest 8 = tile t+1 fully landed
    RDA(ab1, 0); RDB(bb1, 0);
    STG(Ab[0], gA, 0, t + 2);
    LGW_; QUAD(0, 0); BARR_;
    // ---- ph5
    RDB(bb1, 1);
    STG(Ab[0], gA, 1, t + 2);
    LGW_; QUAD(0, 1); BARR_;
    // ---- ph6
    RDA(ab1, 1);
    STG(Bb[1], gB, 0, t + 3);
    LGW_; QUAD(1, 0); BARR_;
    // ---- ph7
    STG(Bb[1], gB, 1, t + 3);
    QUAD(1, 1); BARR_;
  }
  VMW0_;                               // drain tail stages

  // epilogue: per-wave 128x64 block
#pragma unroll
  for (int mi = 0; mi < 8; ++mi) {
#pragma unroll
    for (int ni = 0; ni < 4; ++ni) {
#pragma unroll
      for (int j = 0; j < 4; ++j) {
        long row = arow + wr * 128 + mi * 16 + q4 * 4 + j;
        long col = bcol + wc * 64 + ni * 16 + l15;
        float v = acc[mi][ni][j];
        if constexpr (EPI == 0) {
          int bb = (int)(row >> 11), ss = (int)(row & 2047);
          int hh = (int)(col >> 6) & 15, dd = (int)(col & 63);
          size_t idx = (((size_t)(bb * H_ + hh)) * S_ + ss) * DK_ + dd;
          if (col < 1024) outb[idx]  = (bf16)((v + bias[col]) * scale);
          else            outb2[idx] = (bf16)(v + bias2[col - 1024]);
        } else if constexpr (EPI == 1) {
          size_t idx = (size_t)row * N + col;
          outf[idx] = v + bias[col] + resid[idx];
        } else {
          size_t idx = (size_t)row * N + col;
          float tt = v + bias[col];
          outb[idx] = (bf16)(0.5f * tt * (1.0f + erff(tt * 0.70710678118654752f)));
        }
      }
    }
  }
#undef STG
#undef RDA
#undef RDB
#undef QUAD
}

// =====================================================================
// Flash attention, values == K (reference quirk). UNCHANGED this round.
// =====================================================================
__global__ __launch_bounds__(256)
void attn_fwd(const bf16* __restrict__ Q, const bf16* __restrict__ Kk,
              const bf16* __restrict__ KT, const int* __restrict__ mask,
              bf16* __restrict__ O) {
  __shared__ __align__(16) char Kl[2][64 * 128];  // swizzled [kv][d]
  __shared__ __align__(16) char Vl[2][64 * 128];  // swizzled [d][kv]
  __shared__ __align__(16) char Pl[4][16 * 128];  // swizzled per-wave P

  const int tid = threadIdx.x, wave = tid >> 6, lane = tid & 63;
  const int bh = blockIdx.y, b = bh >> 4, h = bh & 15;
  const int q0 = blockIdx.x * 64;
  const int l15 = lane & 15, q4 = lane >> 4;

  const bf16* Qp = Q  + (size_t)bh * S_ * DK_;
  const bf16* Kp = Kk + (size_t)bh * S_ * DK_;
  const bf16* Tp = KT + (size_t)bh * DK_ * S_;

  const int qrow = q0 + wave * 16 + l15;
  const bf16x8 qf0 = *(const bf16x8*)&Qp[(size_t)qrow * 64 + q4 * 8];
  const bf16x8 qf1 = *(const bf16x8*)&Qp[(size_t)qrow * 64 + 32 + q4 * 8];

  // mask-zero scan, once per block (mask is [B,1,1,S]: loop-invariant)
  int lz = 0;
  for (int i = tid; i < S_; i += 256) lz |= (mask[b * S_ + i] == 0);
  const bool anyz = __syncthreads_or(lz) != 0;

  const int c0 = tid * 2, c1 = tid * 2 + 1;
  const int sr0 = c0 >> 3, sb0 = c0 & 7;
  const int sr1 = c1 >> 3, sb1 = c1 & 7;

  int poff[16];
#pragma unroll
  for (int nt = 0; nt < 4; ++nt)
#pragma unroll
    for (int j = 0; j < 4; ++j) {
      int r = q4 * 4 + j;
      poff[nt * 4 + j] = r * 128 + ((((nt * 16 + l15) * 2)) ^ ((r & 7) << 4));
    }

  bf16x8 onesv;
#pragma unroll
  for (int i = 0; i < 8; ++i) onesv[i] = (bf16)1.0f;

  f32x4 o[4] = {};
  f32x4 ol = {};
  float m_r[4];
#pragma unroll
  for (int j = 0; j < 4; ++j) m_r[j] = -__builtin_inff();

  bf16x8 a0 = *(const bf16x8*)&Kp[(size_t)sr0 * 64 + sb0 * 8];
  bf16x8 a1 = *(const bf16x8*)&Kp[(size_t)sr1 * 64 + sb1 * 8];
  bf16x8 t0 = *(const bf16x8*)&Tp[(size_t)sr0 * S_ + sb0 * 8];
  bf16x8 t1 = *(const bf16x8*)&Tp[(size_t)sr1 * S_ + sb1 * 8];
  *(bf16x8*)swzp(Kl[0], sr0, sb0 * 16) = a0;
  *(bf16x8*)swzp(Kl[0], sr1, sb1 * 16) = a1;
  *(bf16x8*)swzp(Vl[0], sr0, sb0 * 16) = t0;
  *(bf16x8*)swzp(Vl[0], sr1, sb1 * 16) = t1;
  int cur = 0;

  for (int k0 = 0; k0 < S_; k0 += 64) {
    __syncthreads();

    const int nk = k0 + 64;
    if (nk < S_) {
      a0 = *(const bf16x8*)&Kp[(size_t)(nk + sr0) * 64 + sb0 * 8];
      a1 = *(const bf16x8*)&Kp[(size_t)(nk + sr1) * 64 + sb1 * 8];
      t0 = *(const bf16x8*)&Tp[(size_t)sr0 * S_ + nk + sb0 * 8];
      t1 = *(const bf16x8*)&Tp[(size_t)sr1 * S_ + nk + sb1 * 8];
    }

    f32x4 s[4];
#pragma unroll
    for (int nt = 0; nt < 4; ++nt) {
      bf16x8 kf0 = *(const bf16x8*)swzp(Kl[cur], nt * 16 + l15, q4 * 16);
      bf16x8 kf1 = *(const bf16x8*)swzp(Kl[cur], nt * 16 + l15, 64 + q4 * 16);
      f32x4 z = {};
      z     = __builtin_amdgcn_mfma_f32_16x16x32_bf16(qf0, kf0, z, 0, 0, 0);
      s[nt] = __builtin_amdgcn_mfma_f32_16x16x32_bf16(qf1, kf1, z, 0, 0, 0);
    }
    if (anyz) {
#pragma unroll
      for (int nt = 0; nt < 4; ++nt) {
        int m2 = mask[b * S_ + k0 + nt * 16 + l15];
        if (m2 == 0) {
#pragma unroll
          for (int j = 0; j < 4; ++j) s[nt][j] = -1e9f;
        }
      }
    }

    float tm[4];
#pragma unroll
    for (int j = 0; j < 4; ++j)
      tm[j] = fmaxf(fmaxf(s[0][j], s[1][j]), fmaxf(s[2][j], s[3][j]));
    bool ok = true;
#pragma unroll
    for (int j = 0; j < 4; ++j) ok = ok && (tm[j] <= m_r[j] + 8.0f);
    if (!__all(ok)) {
#pragma unroll
      for (int d = 1; d < 16; d <<= 1)
#pragma unroll
        for (int j = 0; j < 4; ++j)
          tm[j] = fmaxf(tm[j], __shfl_xor(tm[j], d));
#pragma unroll
      for (int j = 0; j < 4; ++j) {
        float mn = fmaxf(m_r[j], tm[j]);
        float sf = __builtin_amdgcn_exp2f(m_r[j] - mn);
        m_r[j] = mn;
        ol[j] *= sf;
#pragma unroll
        for (int nf = 0; nf < 4; ++nf) o[nf][j] *= sf;
      }
    }

#pragma unroll
    for (int nt = 0; nt < 4; ++nt)
#pragma unroll
      for (int j = 0; j < 4; ++j)
        *(bf16*)(&Pl[wave][0] + poff[nt * 4 + j]) =
            (bf16)__builtin_amdgcn_exp2f(s[nt][j] - m_r[j]);

    const bf16x8 pf0 = *(const bf16x8*)swzp(Pl[wave], l15, q4 * 16);
    const bf16x8 pf1 = *(const bf16x8*)swzp(Pl[wave], l15, 64 + q4 * 16);

    ol = __builtin_amdgcn_mfma_f32_16x16x32_bf16(pf0, onesv, ol, 0, 0, 0);
    ol = __builtin_amdgcn_mfma_f32_16x16x32_bf16(pf1, onesv, ol, 0, 0, 0);

#pragma unroll
    for (int nf = 0; nf < 4; ++nf) {
      bf16x8 vf0 = *(const bf16x8*)swzp(Vl[cur], nf * 16 + l15, q4 * 16);
      bf16x8 vf1 = *(const bf16x8*)swzp(Vl[cur], nf * 16 + l15, 64 + q4 * 16);
      o[nf] = __builtin_amdgcn_mfma_f32_16x16x32_bf16(pf0, vf0, o[nf], 0, 0, 0);
      o[nf] = __builtin_amdgcn_mfma_f32_16x16x32_bf16(pf1, vf1, o[nf], 0, 0, 0);
    }

    if (nk < S_) {
      *(bf16x8*)swzp(Kl[cur ^ 1], sr0, sb0 * 16) = a0;
      *(bf16x8*)swzp(Kl[cur ^ 1], sr1, sb1 * 16) = a1;
      *(bf16x8*)swzp(Vl[cur ^ 1], sr0, sb0 * 16) = t0;
      *(bf16x8*)swzp(Vl[cur ^ 1], sr1, sb1 * 16) = t1;
    }
    cur ^= 1;
  }

#pragma unroll
  for (int nf = 0; nf < 4; ++nf)
#pragma unroll
    for (int j = 0; j < 4; ++j) {
      int row = q0 + wave * 16 + q4 * 4 + j;
      int col = h * 64 + nf * 16 + l15;
      O[((size_t)b * S_ + row) * D_ + col] = (bf16)(o[nf][j] / ol[j]);
    }
}

// =====================================================================
extern "C" void kernel_launch(void* const* d_in, const int* in_sizes, int n_in,
                              void* d_out, int out_size, void* d_ws, size_t ws_size,
                              hipStream_t stream) {
  const float* x    = (const float*)d_in[0];
  const int*   mask = (const int*)d_in[1];
  const float* Wq   = (const float*)d_in[2];
  const float* bq   = (const float*)d_in[3];
  const float* Wk   = (const float*)d_in[4];
  const float* bk   = (const float*)d_in[5];
  // d_in[6]=Wv, d_in[7]=bv: dead code in the reference (value == key)
  const float* Wo   = (const float*)d_in[8];
  const float* bo   = (const float*)d_in[9];
  const float* ln1g = (const float*)d_in[10];
  const float* ln1b = (const float*)d_in[11];
  const float* W1   = (const float*)d_in[12];
  const float* b1   = (const float*)d_in[13];
  const float* W2   = (const float*)d_in[14];
  const float* b2   = (const float*)d_in[15];
  const float* ln2g = (const float*)d_in[16];
  const float* ln2b = (const float*)d_in[17];
  float* out = (float*)d_out;

  char* w = (char*)d_ws;
  auto alloc = [&](size_t bytes) {
    void* p = (void*)w;
    w += (bytes + 255) & ~(size_t)255;
    return p;
  };
  bf16* xln  = (bf16*)alloc((size_t)M_ * D_ * 2);
  bf16* WqkT = (bf16*)alloc((size_t)2 * D_ * D_ * 2);
  bf16* WoT  = (bf16*)alloc((size_t)D_ * D_ * 2);
  bf16* W1T  = (bf16*)alloc((size_t)D_ * DFF_ * 2);
  bf16* W2T  = (bf16*)alloc((size_t)D_ * DFF_ * 2);
  bf16* Qt   = (bf16*)alloc((size_t)M_ * D_ * 2);
  bf16* Kt   = (bf16*)alloc((size_t)M_ * D_ * 2);
  bf16* KTt  = (bf16*)alloc((size_t)M_ * D_ * 2);
  bf16* attn = (bf16*)alloc((size_t)M_ * D_ * 2);
  float* x2  = (float*)alloc((size_t)M_ * D_ * 4);
  bf16* h2   = (bf16*)alloc((size_t)M_ * D_ * 2);
  bf16* act  = (bf16*)alloc((size_t)M_ * DFF_ * 2);

  tcast_all<<<11264, dim3(32, 8), 0, stream>>>(Wq, Wk, Wo, W1, W2,
                                               WqkT, WoT, W1T, W2T);

  ln_fwd<<<M_, 256, 0, stream>>>(x, ln1g, ln1b, xln);

  // fused Q+K projection; Q scale (1/8)*log2e folded (exp2-domain softmax)
  gemm8p<0, 1024><<<dim3(8, 32), 512, 0, stream>>>(
      xln, WqkT, 2048, bq, bk, nullptr,
      0.125f * 1.4426950408889634f, nullptr, Qt, Kt);

  ktrans<<<dim3(S_ / 64, B_ * H_), 256, 0, stream>>>(Kt, KTt);

  attn_fwd<<<dim3(S_ / 64, B_ * H_), 256, 0, stream>>>(Qt, Kt, KTt, mask, attn);

  // x2 = x + attn @ Wo + bo   (f32)
  gemm8p<1, 1024><<<dim3(4, 32), 512, 0, stream>>>(
      attn, WoT, 1024, bo, nullptr, x, 1.0f, x2, nullptr, nullptr);

  ln_fwd<<<M_, 256, 0, stream>>>(x2, ln2g, ln2b, h2);

  // act = gelu(h2 @ W1 + b1)  (bf16)
  gemm8p<2, 1024><<<dim3(16, 32), 512, 0, stream>>>(
      h2, W1T, 4096, b1, nullptr, nullptr, 1.0f, nullptr, act, nullptr);

  // out = x2 + act @ W2 + b2  (f32)
  gemm8p<1, 4096><<<dim3(4, 32), 512, 0, stream>>>(
      act, W2T, 1024, b2, nullptr, x2, 1.0f, out, nullptr, nullptr);
}